// Round 1
// baseline (1873.263 us; speedup 1.0000x reference)
//
#include <hip/hip_runtime.h>

// RNN_16492674416646: h_t = tanh(x_t W_ih^T + b_ih + b_hh + h_{t-1} W_hh^T),
// out_t = h_t W_out^T + b_out. T=2048, B=128, IN=2, H=200, OUT=1, fp32.
//
// One persistent block per batch element (128 blocks, 512 threads).
// W_hh lives in registers: thread (s,g) holds rows {2g,2g+1} x k-slice [40s,40s+40).
// h broadcast from LDS as float4 (1 LDS op per 8 FMAs). 5 k-slice partials
// reduced through LDS. Head fused via wave-0 shfl reduction.

static constexpr int T = 2048;
static constexpr int B = 128;
static constexpr int H = 200;
static constexpr int KS = 40;     // k-slice width
static constexpr int SLICES = 5;  // 5 * 40 = 200

__global__ __launch_bounds__(512, 2)
void rnn_fused(const float* __restrict__ x,     // [T,B,2]
               const float* __restrict__ W_ih,  // [H,2]
               const float* __restrict__ W_hh,  // [H,H]
               const float* __restrict__ b_ih,  // [H]
               const float* __restrict__ b_hh,  // [H]
               const float* __restrict__ W_out, // [1,H]
               const float* __restrict__ b_out, // [1]
               float* __restrict__ out)         // [T,B]
{
    const int b   = blockIdx.x;
    const int tid = threadIdx.x;
    const int s   = tid / 100;        // k-slice id 0..4 (for tid<500)
    const int g   = tid % 100;        // j-group: rows j=2g, 2g+1
    const bool active = (tid < 500);
    const int j0 = 2 * g;
    const int k0 = s * KS;

    __shared__ float h[H];             // current hidden state (broadcast source)
    __shared__ float part[SLICES][H];  // k-slice partial dot products
    __shared__ float headv[256];       // h*W_out products (tail zeroed)

    // --- one-time: W_hh slice into registers (80 VGPRs/thread) ---
    float w0[KS], w1[KS];
    if (active) {
#pragma unroll
        for (int i = 0; i < KS; ++i) {
            w0[i] = W_hh[j0 * H + k0 + i];
            w1[i] = W_hh[(j0 + 1) * H + k0 + i];
        }
    }

    // --- one-time: phase-2 per-row constants (threads 0..199 own row tid) ---
    float wih0 = 0.f, wih1 = 0.f, bias = 0.f, wout = 0.f;
    if (tid < H) {
        wih0 = W_ih[tid * 2 + 0];
        wih1 = W_ih[tid * 2 + 1];
        bias = b_ih[tid] + b_hh[tid];
        wout = W_out[tid];
    }
    const float bo = b_out[0];

    if (tid < H) h[tid] = 0.f;         // h_0 = 0
    if (tid < 256) headv[tid] = 0.f;
    __syncthreads();

    const float* xp = x + 2 * b;
    float* op = out + b;

    for (int t = 0; t < T; ++t) {
        // x_t for this batch (8 B, L2-resident; issued early, used in phase 2)
        const float x0 = xp[(size_t)t * (B * 2) + 0];
        const float x1 = xp[(size_t)t * (B * 2) + 1];

        // --- phase 1: partial dot products, W in regs, h broadcast from LDS ---
        if (active) {
            float a0 = 0.f, a1 = 0.f, a2 = 0.f, a3 = 0.f;  // 4 indep FMA chains
#pragma unroll
            for (int i = 0; i < KS; i += 4) {
                const float4 hv = *(const float4*)&h[k0 + i];
                a0 = fmaf(w0[i + 0], hv.x, a0);
                a1 = fmaf(w1[i + 0], hv.x, a1);
                a2 = fmaf(w0[i + 1], hv.y, a2);
                a3 = fmaf(w1[i + 1], hv.y, a3);
                a0 = fmaf(w0[i + 2], hv.z, a0);
                a1 = fmaf(w1[i + 2], hv.z, a1);
                a2 = fmaf(w0[i + 3], hv.w, a2);
                a3 = fmaf(w1[i + 3], hv.w, a3);
            }
            part[s][j0]     = a0 + a2;   // ds_write_b64
            part[s][j0 + 1] = a1 + a3;
        }
        __syncthreads();

        // --- phase 2: reduce slices, add input proj, tanh, stage head terms ---
        if (tid < H) {
            const float sum = part[0][tid] + part[1][tid] + part[2][tid]
                            + part[3][tid] + part[4][tid];
            const float pre = sum + fmaf(x0, wih0, fmaf(x1, wih1, bias));
            // tanh(x) = 1 - 2/(e^{2x}+1); overflow -> inf -> 1, underflow -> -1
            const float e  = __expf(2.f * pre);
            const float th = 1.f - 2.f / (e + 1.f);
            h[tid]     = th;          // safe: phase-1 readers passed barrier 1
            headv[tid] = th * wout;
        }
        __syncthreads();

        // --- head: out[t,b] = sum_j h[j]*W_out[j] + b_out, on wave 0 ---
        if (tid < 64) {
            float v = headv[tid] + headv[tid + 64] + headv[tid + 128]
                    + ((tid + 192) < H ? headv[tid + 192] : 0.f);
#pragma unroll
            for (int off = 32; off > 0; off >>= 1)
                v += __shfl_down(v, off, 64);
            if (tid == 0) op[(size_t)t * B] = v + bo;
        }
    }
}

extern "C" void kernel_launch(void* const* d_in, const int* in_sizes, int n_in,
                              void* d_out, int out_size, void* d_ws, size_t ws_size,
                              hipStream_t stream) {
    const float* x     = (const float*)d_in[0];
    const float* W_ih  = (const float*)d_in[1];
    const float* W_hh  = (const float*)d_in[2];
    const float* b_ih  = (const float*)d_in[3];
    const float* b_hh  = (const float*)d_in[4];
    const float* W_out = (const float*)d_in[5];
    const float* b_out = (const float*)d_in[6];
    float* out = (float*)d_out;

    rnn_fused<<<B, 512, 0, stream>>>(x, W_ih, W_hh, b_ih, b_hh, W_out, b_out, out);
}

// Round 2
// 1445.939 us; speedup vs baseline: 1.2955x; 1.2955x over previous
//
#include <hip/hip_runtime.h>

// RNN_16492674416646: h_t = tanh(x_t W_ih^T + b_ih + b_hh + h_{t-1} W_hh^T),
// out_t = h_t W_out^T + b_out. T=2048, B=128, IN=2, H=200, OUT=1, fp32.
//
// One persistent block per batch element (128 blocks, 1024 threads).
// R2 change vs R1: R1's 80-float/thread weight arrays were demoted to scratch
// (VGPR=56, WRITE_SIZE 8MB, ~2180 cyc/step of L2 replay). Now 1024 threads x
// 40 weights (10x float4), unconditional constant-index access -> registers.
// x column staged to LDS once (kills per-step HBM-latency load).

static constexpr int T = 2048;
static constexpr int B = 128;
static constexpr int H = 200;
static constexpr int KS = 40;     // k-slice width
static constexpr int SLICES = 5;  // 5 * 40 = 200
static constexpr int NTHR = 1024;

__global__ __launch_bounds__(NTHR, 4)
void rnn_fused(const float* __restrict__ x,     // [T,B,2]
               const float* __restrict__ W_ih,  // [H,2]
               const float* __restrict__ W_hh,  // [H,H]
               const float* __restrict__ b_ih,  // [H]
               const float* __restrict__ b_hh,  // [H]
               const float* __restrict__ W_out, // [1,H]
               const float* __restrict__ b_out, // [1]
               float* __restrict__ out)         // [T,B]
{
    const int b   = blockIdx.x;
    const int tid = threadIdx.x;

    int s = tid / H;                  // slice 0..4 (tid<1000)
    int j = tid - s * H;              // row 0..199
    const bool active = (tid < SLICES * H);
    if (!active) { s = SLICES - 1; j = H - 1; }   // clamp: harmless valid work
    const int k0 = s * KS;

    __shared__ float h[H];             // current hidden state (broadcast source)
    __shared__ float part[SLICES][H];  // k-slice partial dot products
    __shared__ float headv[256];       // h*W_out products (tail zeroed)
    __shared__ float xs[2 * T];        // this block's x column, staged once

    // --- one-time: W_hh slice into registers (10 float4 = 40 VGPRs) ---
    // Row j is 800 B from row j+1; slice offset 160*s B -> 16B-aligned.
    const float4* wp = (const float4*)(W_hh + j * H + k0);
    float4 w4[10];
#pragma unroll
    for (int i = 0; i < 10; ++i) w4[i] = wp[i];

    // --- one-time: stage x[:, b, :] into LDS (16 KB) ---
    for (int idx = tid; idx < T; idx += NTHR) {
        const float2 v = *(const float2*)(x + (size_t)idx * (B * 2) + 2 * b);
        xs[2 * idx + 0] = v.x;
        xs[2 * idx + 1] = v.y;
    }

    // --- one-time: phase-2 per-row constants (threads 0..199 own row tid) ---
    float wih0 = 0.f, wih1 = 0.f, bias = 0.f, wout = 0.f;
    if (tid < H) {
        wih0 = W_ih[tid * 2 + 0];
        wih1 = W_ih[tid * 2 + 1];
        bias = b_ih[tid] + b_hh[tid];
        wout = W_out[tid];
    }
    const float bo = b_out[0];

    if (tid < H) h[tid] = 0.f;         // h_0 = 0
    if (tid < 256) headv[tid] = 0.f;
    __syncthreads();

    float* op = out + b;

    for (int t = 0; t < T; ++t) {
        // --- phase 1: partial dot product, W in regs, h broadcast from LDS ---
        {
            const float4* hv4 = (const float4*)&h[k0];
            float a0 = 0.f, a1 = 0.f, a2 = 0.f, a3 = 0.f;  // 4 indep chains
#pragma unroll
            for (int i = 0; i < 10; ++i) {
                const float4 hv = hv4[i];
                a0 = fmaf(w4[i].x, hv.x, a0);
                a1 = fmaf(w4[i].y, hv.y, a1);
                a2 = fmaf(w4[i].z, hv.z, a2);
                a3 = fmaf(w4[i].w, hv.w, a3);
            }
            if (active) part[s][j] = (a0 + a2) + (a1 + a3);
        }
        __syncthreads();

        // --- phase 2: reduce slices, add input proj, tanh, stage head terms ---
        if (tid < H) {
            const float sum = part[0][tid] + part[1][tid] + part[2][tid]
                            + part[3][tid] + part[4][tid];
            const float x0 = xs[2 * t + 0];
            const float x1 = xs[2 * t + 1];
            const float pre = sum + fmaf(x0, wih0, fmaf(x1, wih1, bias));
            // tanh(x) = 1 - 2/(e^{2x}+1); overflow -> inf -> 1, underflow -> -1
            const float e  = __expf(2.f * pre);
            const float th = 1.f - 2.f / (e + 1.f);
            h[tid]     = th;          // safe: phase-1 readers passed barrier 1
            headv[tid] = th * wout;
        }
        __syncthreads();

        // --- head: out[t,b] = sum_j h[j]*W_out[j] + b_out, on wave 0 ---
        // (overlaps next iteration's phase 1 on the other 15 waves)
        if (tid < 64) {
            float v = headv[tid] + headv[tid + 64] + headv[tid + 128]
                    + ((tid + 192) < H ? headv[tid + 192] : 0.f);
#pragma unroll
            for (int off = 32; off > 0; off >>= 1)
                v += __shfl_down(v, off, 64);
            if (tid == 0) op[(size_t)t * B] = v + bo;
        }
    }
}

extern "C" void kernel_launch(void* const* d_in, const int* in_sizes, int n_in,
                              void* d_out, int out_size, void* d_ws, size_t ws_size,
                              hipStream_t stream) {
    const float* x     = (const float*)d_in[0];
    const float* W_ih  = (const float*)d_in[1];
    const float* W_hh  = (const float*)d_in[2];
    const float* b_ih  = (const float*)d_in[3];
    const float* b_hh  = (const float*)d_in[4];
    const float* W_out = (const float*)d_in[5];
    const float* b_out = (const float*)d_in[6];
    float* out = (float*)d_out;

    rnn_fused<<<B, NTHR, 0, stream>>>(x, W_ih, W_hh, b_ih, b_hh, W_out, b_out, out);
}